// Round 2
// baseline (12681.383 us; speedup 1.0000x reference)
//
#include <hip/hip_runtime.h>

// Problem constants (fixed by the reference): B=64, T=512, D=1024, R=1024, O=1024
#define BB 64
#define TT 512
#define DD 1024
#define RR 1024

typedef __bf16 bf16x8 __attribute__((ext_vector_type(8)));
typedef float f32x4 __attribute__((ext_vector_type(4)));
typedef unsigned short us4 __attribute__((ext_vector_type(4)));

__device__ inline unsigned short f2bf(float f) {
  unsigned int u = __float_as_uint(f);
  u = (u + 0x7fffu + ((u >> 16) & 1u)) >> 16;   // RNE
  return (unsigned short)u;
}
__device__ inline float bf2f(unsigned short b) {
  return __uint_as_float(((unsigned int)b) << 16);
}

// ---- fp32 -> bf16 vectorized convert (n4 = n/4 groups) ----
__global__ void k_f2b4(const float* __restrict__ in, unsigned short* __restrict__ out, int n4) {
  int i = blockIdx.x * blockDim.x + threadIdx.x;
  if (i < n4) {
    const float4 v = ((const float4*)in)[i];
    us4 o;
    o.x = f2bf(v.x); o.y = f2bf(v.y); o.z = f2bf(v.z); o.w = f2bf(v.w);
    ((us4*)out)[i] = o;
  }
}

// ---- transpose 1024x1024 fp32 -> bf16 (out[j][k] = in[k][j]) ----
__global__ __launch_bounds__(256) void k_transpose_bf16(
    const float* __restrict__ in, unsigned short* __restrict__ out) {
  __shared__ float tile[32][33];
  const int bx = blockIdx.x * 32, by0 = blockIdx.y * 32;
  const int tx = threadIdx.x, ty = threadIdx.y;  // block (32,8)
#pragma unroll
  for (int r = 0; r < 32; r += 8)
    tile[ty + r][tx] = in[(size_t)(by0 + ty + r) * 1024 + bx + tx];
  __syncthreads();
#pragma unroll
  for (int r = 0; r < 32; r += 8)
    out[(size_t)(bx + ty + r) * 1024 + by0 + tx] = f2bf(tile[tx][ty + r]);
}

// ---- async global->LDS, 16B per lane ----
__device__ inline void gload_lds16(const unsigned short* g, unsigned short* l) {
  __builtin_amdgcn_global_load_lds(
      (const __attribute__((address_space(1))) unsigned int*)g,
      (__attribute__((address_space(3))) unsigned int*)l, 16, 0, 0);
}

// ---- bf16 GEMM, C[m,n] = sum_k A[m,k]*B[n,k], 128x128 tile, BK=32 ----
// EPI==0: out = xhz time-major [T][B][2048] bf16, bias folded (bh for n<1024, bz else)
// EPI==1: out[m*1024+n] bf16 (Mz into Wrec rows 1024..2047; pass outb=Wrec+1024*1024)
template <int EPI>
__global__ __launch_bounds__(256) void gemm_bt(
    const unsigned short* __restrict__ A,
    const unsigned short* __restrict__ Bm,
    const float* __restrict__ bias_h,
    const float* __restrict__ bias_z,
    unsigned short* __restrict__ outb, int K) {
  __shared__ __attribute__((aligned(16))) unsigned short As[128 * 32];
  __shared__ __attribute__((aligned(16))) unsigned short Bs[128 * 32];
  const int tid = threadIdx.x;
  const int m0 = blockIdx.y * 128, n0 = blockIdx.x * 128;
  const int lane = tid & 63, wid = tid >> 6;
  const int l16 = lane & 15, quad = lane >> 4;
  const int wm = (wid & 1) * 64, wn = (wid >> 1) * 64;

  f32x4 acc[4][4] = {};

  const int c0 = tid, c1 = 256 + tid;
  const int rowA0 = c0 >> 2, colA0 = (c0 & 3) << 3;
  const int rowA1 = c1 >> 2, colA1 = (c1 & 3) << 3;

  for (int kk = 0; kk < K; kk += 32) {
    __syncthreads();
    gload_lds16(A + (size_t)(m0 + rowA0) * K + kk + colA0, As + c0 * 8);
    gload_lds16(A + (size_t)(m0 + rowA1) * K + kk + colA1, As + c1 * 8);
    gload_lds16(Bm + (size_t)(n0 + rowA0) * K + kk + colA0, Bs + c0 * 8);
    gload_lds16(Bm + (size_t)(n0 + rowA1) * K + kk + colA1, Bs + c1 * 8);
    __syncthreads();
    bf16x8 af[4], bfr[4];
#pragma unroll
    for (int i = 0; i < 4; ++i) {
      af[i] = *(const bf16x8*)&As[(wm + i * 16 + l16) * 32 + quad * 8];
      bfr[i] = *(const bf16x8*)&Bs[(wn + i * 16 + l16) * 32 + quad * 8];
    }
#pragma unroll
    for (int i = 0; i < 4; ++i)
#pragma unroll
      for (int j = 0; j < 4; ++j)
        acc[i][j] = __builtin_amdgcn_mfma_f32_16x16x32_bf16(af[i], bfr[j], acc[i][j], 0, 0, 0);
  }

#pragma unroll
  for (int i = 0; i < 4; ++i) {
#pragma unroll
    for (int j = 0; j < 4; ++j) {
#pragma unroll
      for (int r = 0; r < 4; ++r) {
        const int m = m0 + wm + i * 16 + quad * 4 + r;
        const int n = n0 + wn + j * 16 + l16;
        float v = acc[i][j][r];
        if (EPI == 0) {
          v += (n < 1024) ? bias_h[n] : bias_z[n - 1024];
          const int b = m >> 9;          // m = b*T + t, T=512
          const int t = m & 511;
          outb[((size_t)(t * 64 + b) << 11) + n] = f2bf(v);
        } else {
          outb[(size_t)m * 1024 + n] = f2bf(v);
        }
      }
    }
  }
}

// ---- persistent cooperative scan over T=512 steps + output GEMM ----
// 128 blocks x 256 threads. Block g owns h-columns [g*8, g*8+8); the 16-wide
// MFMA n-tile = {Whh rows i0..i0+7} U {Mz rows (Wrec rows 1024+i0..)}.
// Custom all-read barrier: each block release-stores flags[g]=t+1 (distinct
// addresses, no RMW contention); wave 0 polls all 128 flags (2 coalesced
// agent-scope loads/lane). Monotone targets -> no reset races.
// Per-thread fp32 master h kept in registers (each thread owns the same two
// (b,i) elements all 512 steps); only the bf16 copy is published globally.
__global__ __launch_bounds__(256) void scan_out_k(
    const unsigned short* __restrict__ xhz,   // [T][B][2048] bf16
    const unsigned short* __restrict__ Wrec,  // [2048][1024] bf16 (Whh ; Mz)
    const unsigned short* __restrict__ Wyb,   // [1024][1024] bf16
    const float* __restrict__ by,
    unsigned short* __restrict__ hb0, unsigned short* __restrict__ hb1,  // bf16 h (double buf)
    unsigned int* __restrict__ flags,
    float* __restrict__ out) {
  __shared__ float red[4][64][20];  // stride 20: quad offset = 80 words -> 2-way (free)
  const int tid = threadIdx.x, g = blockIdx.x;
  const int lane = tid & 63, wid = tid >> 6;
  const int l16 = lane & 15, quad = lane >> 4;
  const int kw = wid * 256;
  const int i0 = g * 8;
  const int brow = (l16 < 8) ? (i0 + l16) : (1024 + i0 + (l16 - 8));
  const unsigned short* Bb = Wrec + (size_t)brow * 1024 + kw + quad * 8;

  // loop-invariant B fragments (16 n-rows x 256 k) -> 32 VGPRs
  bf16x8 bfr[8];
#pragma unroll
  for (int s = 0; s < 8; ++s) bfr[s] = *(const bf16x8*)(Bb + s * 32);

  // per-thread persistent h state: this thread owns (b_0, i0+il) and (b_1, i0+il)
  const int il = tid & 7;
  const int b_0 = tid >> 3;           // p = tid       -> b in [0,32)
  const int b_1 = (256 + tid) >> 3;   // p = 256 + tid -> b in [32,64)
  float hold0 = 0.0f, hold1 = 0.0f;

  unsigned short* hbc = hb0;
  unsigned short* hbn = hb1;

  for (int t = 0; t < TT; ++t) {
    // prefetch this step's input-GEMM terms (independent of h)
    const size_t x0 = ((size_t)(t * 64 + b_0) << 11);
    const size_t x1 = ((size_t)(t * 64 + b_1) << 11);
    const float xh0 = bf2f(xhz[x0 + i0 + il]);
    const float xz0 = bf2f(xhz[x0 + 1024 + i0 + il]);
    const float xh1 = bf2f(xhz[x1 + i0 + il]);
    const float xz1 = bf2f(xhz[x1 + 1024 + i0 + il]);

    f32x4 acc[4] = {};
#pragma unroll
    for (int s = 0; s < 8; ++s) {
#pragma unroll
      for (int mt = 0; mt < 4; ++mt) {
        const bf16x8 afr = *(const bf16x8*)(hbc + (size_t)(mt * 16 + l16) * 1024 + kw + s * 32 + quad * 8);
        acc[mt] = __builtin_amdgcn_mfma_f32_16x16x32_bf16(afr, bfr[s], acc[mt], 0, 0, 0);
      }
    }
#pragma unroll
    for (int mt = 0; mt < 4; ++mt)
#pragma unroll
      for (int r = 0; r < 4; ++r)
        red[wid][mt * 16 + quad * 4 + r][l16] = acc[mt][r];
    __syncthreads();

    // elementwise update for this thread's two fixed (b,i) elements
    {
      const float ph = red[0][b_0][il] + red[1][b_0][il] + red[2][b_0][il] + red[3][b_0][il];
      const float pz = red[0][b_0][il + 8] + red[1][b_0][il + 8] + red[2][b_0][il + 8] + red[3][b_0][il + 8];
      const float z = 1.0f / (1.0f + __expf(-(xz0 + pz)));
      const float hbv = fmaxf(xh0 + ph, 0.0f);
      hold0 = z * hold0 + (1.0f - z) * hbv;
      hbn[b_0 * 1024 + i0 + il] = f2bf(hold0);
    }
    {
      const float ph = red[0][b_1][il] + red[1][b_1][il] + red[2][b_1][il] + red[3][b_1][il];
      const float pz = red[0][b_1][il + 8] + red[1][b_1][il + 8] + red[2][b_1][il + 8] + red[3][b_1][il + 8];
      const float z = 1.0f / (1.0f + __expf(-(xz1 + pz)));
      const float hbv = fmaxf(xh1 + ph, 0.0f);
      hold1 = z * hold1 + (1.0f - z) * hbv;
      hbn[b_1 * 1024 + i0 + il] = f2bf(hold1);
    }

    // ---- custom all-read grid barrier ----
    __syncthreads();  // all waves' hbn stores drained (per-wave vmcnt before s_barrier)
    if (tid == 0) {
      __threadfence();  // agent-scope release: push block's writes to coherence point
      __hip_atomic_store(&flags[g], (unsigned int)(t + 1), __ATOMIC_RELEASE,
                         __HIP_MEMORY_SCOPE_AGENT);
    }
    if (tid < 64) {
      const unsigned int tgt = (unsigned int)(t + 1);
      unsigned int a, b;
      do {
        a = __hip_atomic_load(&flags[tid], __ATOMIC_ACQUIRE, __HIP_MEMORY_SCOPE_AGENT);
        b = __hip_atomic_load(&flags[64 + tid], __ATOMIC_ACQUIRE, __HIP_MEMORY_SCOPE_AGENT);
      } while (__any(a < tgt || b < tgt));
    }
    __syncthreads();
    __threadfence();  // acquire side: invalidate stale cached h before next step's reads

    { unsigned short* tmp = hbc; hbc = hbn; hbn = tmp; }
  }

  // out = h_final @ Wy^T + by ; final h (bf16) is in hbc (== hb0 after 512 swaps)
  if (g < 64) {
    const int o0 = g * 16;
    const unsigned short* Byb = Wyb + (size_t)(o0 + l16) * 1024 + kw + quad * 8;
    f32x4 acc[4] = {};
#pragma unroll
    for (int s = 0; s < 8; ++s) {
      const bf16x8 byf = *(const bf16x8*)(Byb + s * 32);
#pragma unroll
      for (int mt = 0; mt < 4; ++mt) {
        const bf16x8 afr = *(const bf16x8*)(hbc + (size_t)(mt * 16 + l16) * 1024 + kw + s * 32 + quad * 8);
        acc[mt] = __builtin_amdgcn_mfma_f32_16x16x32_bf16(afr, byf, acc[mt], 0, 0, 0);
      }
    }
#pragma unroll
    for (int mt = 0; mt < 4; ++mt)
#pragma unroll
      for (int r = 0; r < 4; ++r)
        red[wid][mt * 16 + quad * 4 + r][l16] = acc[mt][r];
    __syncthreads();
#pragma unroll
    for (int j = 0; j < 4; ++j) {
      const int p = j * 256 + tid;
      const int b = p >> 4, oc = p & 15;
      const float v = red[0][b][oc] + red[1][b][oc] + red[2][b][oc] + red[3][b][oc] + by[o0 + oc];
      out[(size_t)b * 1024 + o0 + oc] = v;
    }
  }
}

extern "C" void kernel_launch(void* const* d_in, const int* in_sizes, int n_in,
                              void* d_out, int out_size, void* d_ws, size_t ws_size,
                              hipStream_t stream) {
  const float* x = (const float*)d_in[0];
  const float* Wxh = (const float*)d_in[1];
  const float* bh = (const float*)d_in[2];
  const float* Whh = (const float*)d_in[3];
  const float* Wxz = (const float*)d_in[4];
  const float* bz = (const float*)d_in[5];
  const float* Whz = (const float*)d_in[6];
  const float* Wy = (const float*)d_in[7];
  const float* by = (const float*)d_in[8];
  float* out = (float*)d_out;

  char* ws = (char*)d_ws;
  size_t off = 0;
  auto alloc = [&](size_t bytes) -> void* {
    void* p = ws + off;
    off += (bytes + 255) & ~(size_t)255;
    return p;
  };
  const size_t nX = (size_t)BB * TT * DD;  // 33554432
  unsigned short* xb = (unsigned short*)alloc(nX * 2);                  // x bf16
  unsigned short* Wcat = (unsigned short*)alloc((size_t)2048 * 1024 * 2);  // [Wxh;Wxz] bf16
  unsigned short* WhzT = (unsigned short*)alloc((size_t)1024 * 1024 * 2);  // Whz^T bf16
  unsigned short* Wrec = (unsigned short*)alloc((size_t)2048 * 1024 * 2);  // [Whh;Mz] bf16
  unsigned short* Wyb = (unsigned short*)alloc((size_t)1024 * 1024 * 2);   // Wy bf16
  unsigned short* xhz = (unsigned short*)alloc((size_t)TT * BB * 2048 * 2);  // 128 MB
  unsigned short* hb0 = (unsigned short*)alloc((size_t)BB * RR * 2);
  unsigned short* hb1 = (unsigned short*)alloc((size_t)BB * RR * 2);
  unsigned int* flags = (unsigned int*)alloc(1024);

  hipMemsetAsync(hb0, 0, (size_t)BB * RR * 2, stream);
  hipMemsetAsync(flags, 0, 1024, stream);

  // weight / input conversions
  k_f2b4<<<dim3((unsigned)(nX / 4 / 256)), 256, 0, stream>>>(x, xb, (int)(nX / 4));
  k_f2b4<<<dim3(1024), 256, 0, stream>>>(Wxh, Wcat, 262144);
  k_f2b4<<<dim3(1024), 256, 0, stream>>>(Wxz, Wcat + 1024 * 1024, 262144);
  k_f2b4<<<dim3(1024), 256, 0, stream>>>(Whh, Wrec, 262144);
  k_f2b4<<<dim3(1024), 256, 0, stream>>>(Wy, Wyb, 262144);
  k_transpose_bf16<<<dim3(32, 32), dim3(32, 8), 0, stream>>>(Whz, WhzT);

  // Mz = Wxz @ Whz  -> Wrec rows 1024..2047
  gemm_bt<1><<<dim3(8, 8), 256, 0, stream>>>(Wcat + 1024 * 1024, WhzT, nullptr, nullptr,
                                             Wrec + (size_t)1024 * 1024, 1024);
  // xhz = x @ [Wxh;Wxz]^T + [bh;bz], time-major
  gemm_bt<0><<<dim3(16, 256), 256, 0, stream>>>(xb, Wcat, bh, bz, xhz, 1024);

  // cooperative launch (co-residency guarantee for the custom barrier)
  const unsigned short* xhz_c = xhz;
  const unsigned short* Wrec_c = Wrec;
  const unsigned short* Wyb_c = Wyb;
  const float* by_c = by;
  void* kargs[] = {(void*)&xhz_c, (void*)&Wrec_c, (void*)&Wyb_c, (void*)&by_c,
                   (void*)&hb0, (void*)&hb1, (void*)&flags, (void*)&out};
  hipLaunchCooperativeKernel((void*)scan_out_k, dim3(128), dim3(256), kargs, 0, stream);
}

// Round 3
// 6358.654 us; speedup vs baseline: 1.9944x; 1.9944x over previous
//
#include <hip/hip_runtime.h>

// Problem constants (fixed by the reference): B=64, T=512, D=1024, R=1024, O=1024
#define BB 64
#define TT 512
#define DD 1024
#define RR 1024

typedef __bf16 bf16x8 __attribute__((ext_vector_type(8)));
typedef float f32x4 __attribute__((ext_vector_type(4)));
typedef unsigned short us4 __attribute__((ext_vector_type(4)));
typedef unsigned long long u64;

union frag_u { u64 q[2]; bf16x8 v; };

__device__ inline unsigned short f2bf(float f) {
  unsigned int u = __float_as_uint(f);
  u = (u + 0x7fffu + ((u >> 16) & 1u)) >> 16;   // RNE
  return (unsigned short)u;
}
__device__ inline float bf2f(unsigned short b) {
  return __uint_as_float(((unsigned int)b) << 16);
}

// ---- fp32 -> bf16 vectorized convert (n4 = n/4 groups) ----
__global__ void k_f2b4(const float* __restrict__ in, unsigned short* __restrict__ out, int n4) {
  int i = blockIdx.x * blockDim.x + threadIdx.x;
  if (i < n4) {
    const float4 v = ((const float4*)in)[i];
    us4 o;
    o.x = f2bf(v.x); o.y = f2bf(v.y); o.z = f2bf(v.z); o.w = f2bf(v.w);
    ((us4*)out)[i] = o;
  }
}

// ---- transpose 1024x1024 fp32 -> bf16 (out[j][k] = in[k][j]) ----
__global__ __launch_bounds__(256) void k_transpose_bf16(
    const float* __restrict__ in, unsigned short* __restrict__ out) {
  __shared__ float tile[32][33];
  const int bx = blockIdx.x * 32, by0 = blockIdx.y * 32;
  const int tx = threadIdx.x, ty = threadIdx.y;  // block (32,8)
#pragma unroll
  for (int r = 0; r < 32; r += 8)
    tile[ty + r][tx] = in[(size_t)(by0 + ty + r) * 1024 + bx + tx];
  __syncthreads();
#pragma unroll
  for (int r = 0; r < 32; r += 8)
    out[(size_t)(bx + ty + r) * 1024 + by0 + tx] = f2bf(tile[tx][ty + r]);
}

// ---- async global->LDS, 16B per lane ----
__device__ inline void gload_lds16(const unsigned short* g, unsigned short* l) {
  __builtin_amdgcn_global_load_lds(
      (const __attribute__((address_space(1))) unsigned int*)g,
      (__attribute__((address_space(3))) unsigned int*)l, 16, 0, 0);
}

// ---- bf16 GEMM, C[m,n] = sum_k A[m,k]*B[n,k], 128x128 tile, BK=32 ----
// EPI==0: out = xhz time-major [T][B][2048] bf16, bias folded (bh for n<1024, bz else)
// EPI==1: out[m*1024+n] bf16 (Mz into Wrec rows 1024..2047)
template <int EPI>
__global__ __launch_bounds__(256) void gemm_bt(
    const unsigned short* __restrict__ A,
    const unsigned short* __restrict__ Bm,
    const float* __restrict__ bias_h,
    const float* __restrict__ bias_z,
    unsigned short* __restrict__ outb, int K) {
  __shared__ __attribute__((aligned(16))) unsigned short As[128 * 32];
  __shared__ __attribute__((aligned(16))) unsigned short Bs[128 * 32];
  const int tid = threadIdx.x;
  const int m0 = blockIdx.y * 128, n0 = blockIdx.x * 128;
  const int lane = tid & 63, wid = tid >> 6;
  const int l16 = lane & 15, quad = lane >> 4;
  const int wm = (wid & 1) * 64, wn = (wid >> 1) * 64;

  f32x4 acc[4][4] = {};

  const int c0 = tid, c1 = 256 + tid;
  const int rowA0 = c0 >> 2, colA0 = (c0 & 3) << 3;
  const int rowA1 = c1 >> 2, colA1 = (c1 & 3) << 3;

  for (int kk = 0; kk < K; kk += 32) {
    __syncthreads();
    gload_lds16(A + (size_t)(m0 + rowA0) * K + kk + colA0, As + c0 * 8);
    gload_lds16(A + (size_t)(m0 + rowA1) * K + kk + colA1, As + c1 * 8);
    gload_lds16(Bm + (size_t)(n0 + rowA0) * K + kk + colA0, Bs + c0 * 8);
    gload_lds16(Bm + (size_t)(n0 + rowA1) * K + kk + colA1, Bs + c1 * 8);
    __syncthreads();
    bf16x8 af[4], bfr[4];
#pragma unroll
    for (int i = 0; i < 4; ++i) {
      af[i] = *(const bf16x8*)&As[(wm + i * 16 + l16) * 32 + quad * 8];
      bfr[i] = *(const bf16x8*)&Bs[(wn + i * 16 + l16) * 32 + quad * 8];
    }
#pragma unroll
    for (int i = 0; i < 4; ++i)
#pragma unroll
      for (int j = 0; j < 4; ++j)
        acc[i][j] = __builtin_amdgcn_mfma_f32_16x16x32_bf16(af[i], bfr[j], acc[i][j], 0, 0, 0);
  }

#pragma unroll
  for (int i = 0; i < 4; ++i) {
#pragma unroll
    for (int j = 0; j < 4; ++j) {
#pragma unroll
      for (int r = 0; r < 4; ++r) {
        const int m = m0 + wm + i * 16 + quad * 4 + r;
        const int n = n0 + wn + j * 16 + l16;
        float v = acc[i][j][r];
        if (EPI == 0) {
          v += (n < 1024) ? bias_h[n] : bias_z[n - 1024];
          const int b = m >> 9;          // m = b*T + t, T=512
          const int t = m & 511;
          outb[((size_t)(t * 64 + b) << 11) + n] = f2bf(v);
        } else {
          outb[(size_t)m * 1024 + n] = f2bf(v);
        }
      }
    }
  }
}

// ---- persistent scan over T=512 steps + output GEMM ----
// 128 blocks x 256 threads. Block g owns h-cols [g*8,g*8+8); 16-wide MFMA
// n-tile = {Whh rows i0..} U {Mz rows (Wrec 1024+i0..)}. Waves split K.
//
// KEY (round 3): h and flags cross blocks ONLY via relaxed AGENT-scope
// atomics (sc0 sc1 -> coherence point/L3, bypass non-coherent per-XCD L2s).
// NO fences anywhere in the loop -> no buffer_wbl2/buffer_inv L2 tag-walks,
// which rounds 1-2 showed cost ~23us/step. Ordering: __syncthreads() drains
// vmcnt per wave before s_barrier, so h-stores are at L3 before the flag
// store. Within this launch, h buffers are NEVER touched by cached stores,
// so no dirty L2 line can clobber L3 (pre-launch memset/poison dirty lines
// are flushed by their own dispatch-end release).
__global__ __launch_bounds__(256) void scan_out_k(
    const unsigned short* __restrict__ xhz,   // [T][B][2048] bf16
    const unsigned short* __restrict__ Wrec,  // [2048][1024] bf16 (Whh ; Mz)
    const unsigned short* __restrict__ Wyb,   // [1024][1024] bf16
    const float* __restrict__ by,
    unsigned short* __restrict__ hb0, unsigned short* __restrict__ hb1,
    unsigned int* __restrict__ flags,
    float* __restrict__ out) {
  __shared__ float red[4][64][20];  // stride 20 -> <=2-way bank aliasing (free)
  const int tid = threadIdx.x, g = blockIdx.x;
  const int lane = tid & 63, wid = tid >> 6;
  const int l16 = lane & 15, quad = lane >> 4;
  const int kw = wid * 256;         // this wave's K slice (bf16 elements)
  const int kw4 = wid * 64;         // same in u64 units
  const int i0 = g * 8;
  const int brow = (l16 < 8) ? (i0 + l16) : (1024 + i0 + (l16 - 8));
  const unsigned short* Bb = Wrec + (size_t)brow * 1024 + kw + quad * 8;

  // loop-invariant B fragments (16 n-rows x 256 k) -> 32 VGPRs, plain cached
  bf16x8 bfr[8];
#pragma unroll
  for (int s = 0; s < 8; ++s) bfr[s] = *(const bf16x8*)(Bb + s * 32);

  // elementwise ownership: threads 0..127 each own (b, i0+il4*4 .. +4)
  const int eb = tid >> 1, eil4 = tid & 1;
  const int ibase = i0 + eil4 * 4;
  float hold[4] = {0.f, 0.f, 0.f, 0.f};  // fp32 master h, lives in registers

  unsigned short* hbc = hb0;
  unsigned short* hbn = hb1;

  for (int t = 0; t < TT; ++t) {
    // prefetch this step's input-GEMM terms (plain cached loads, read-only)
    us4 xhv = {}, xzv = {};
    if (tid < 128) {
      const size_t x0 = ((size_t)(t * 64 + eb) << 11);
      xhv = *(const us4*)(xhz + x0 + ibase);
      xzv = *(const us4*)(xhz + x0 + 1024 + ibase);
    }

    // MFMA over h: A fragments via relaxed AGENT atomics (L2-bypass, coherent)
    f32x4 acc[4] = {};
    const u64* hq = (const u64*)hbc;
#pragma unroll
    for (int sh = 0; sh < 2; ++sh) {
      u64 aq[4][4][2];
#pragma unroll
      for (int s2 = 0; s2 < 4; ++s2) {
#pragma unroll
        for (int mt = 0; mt < 4; ++mt) {
          const int s = sh * 4 + s2;
          u64* p = (u64*)&hq[(mt * 16 + l16) * 256 + kw4 + s * 8 + quad * 2];
          aq[s2][mt][0] = __hip_atomic_load(p, __ATOMIC_RELAXED, __HIP_MEMORY_SCOPE_AGENT);
          aq[s2][mt][1] = __hip_atomic_load(p + 1, __ATOMIC_RELAXED, __HIP_MEMORY_SCOPE_AGENT);
        }
      }
#pragma unroll
      for (int s2 = 0; s2 < 4; ++s2) {
#pragma unroll
        for (int mt = 0; mt < 4; ++mt) {
          frag_u f;
          f.q[0] = aq[s2][mt][0];
          f.q[1] = aq[s2][mt][1];
          acc[mt] = __builtin_amdgcn_mfma_f32_16x16x32_bf16(f.v, bfr[sh * 4 + s2], acc[mt], 0, 0, 0);
        }
      }
    }
#pragma unroll
    for (int mt = 0; mt < 4; ++mt)
#pragma unroll
      for (int r = 0; r < 4; ++r)
        red[wid][mt * 16 + quad * 4 + r][l16] = acc[mt][r];
    __syncthreads();

    // elementwise update: 4 consecutive h elements per thread (tid<128)
    if (tid < 128) {
      float ph[4] = {0.f, 0.f, 0.f, 0.f}, pz[4] = {0.f, 0.f, 0.f, 0.f};
#pragma unroll
      for (int w = 0; w < 4; ++w) {
        const float4 a = *(const float4*)&red[w][eb][eil4 * 4];
        const float4 c = *(const float4*)&red[w][eb][8 + eil4 * 4];
        ph[0] += a.x; ph[1] += a.y; ph[2] += a.z; ph[3] += a.w;
        pz[0] += c.x; pz[1] += c.y; pz[2] += c.z; pz[3] += c.w;
      }
      u64 pk = 0;
#pragma unroll
      for (int j = 0; j < 4; ++j) {
        const float xh = bf2f(xhv[j]);
        const float xz = bf2f(xzv[j]);
        const float z = 1.0f / (1.0f + __expf(-(xz + pz[j])));
        const float hbv = fmaxf(xh + ph[j], 0.0f);
        hold[j] = z * hold[j] + (1.0f - z) * hbv;
        pk |= (u64)f2bf(hold[j]) << (16 * j);
      }
      __hip_atomic_store((u64*)(hbn + eb * 1024 + ibase), pk,
                         __ATOMIC_RELAXED, __HIP_MEMORY_SCOPE_AGENT);
    }

    // ---- fence-free grid barrier (flags via L3, no cache maintenance) ----
    __syncthreads();  // drains each wave's vmcnt -> all h-stores at L3
    if (tid == 0)
      __hip_atomic_store(&flags[g], (unsigned int)(t + 1),
                         __ATOMIC_RELAXED, __HIP_MEMORY_SCOPE_AGENT);
    if (tid < 64) {
      const unsigned int tgt = (unsigned int)(t + 1);
      unsigned int a, b;
      do {
        a = __hip_atomic_load(&flags[tid], __ATOMIC_RELAXED, __HIP_MEMORY_SCOPE_AGENT);
        b = __hip_atomic_load(&flags[64 + tid], __ATOMIC_RELAXED, __HIP_MEMORY_SCOPE_AGENT);
      } while (__any(a < tgt || b < tgt));
    }
    __syncthreads();

    { unsigned short* tmp = hbc; hbc = hbn; hbn = tmp; }
  }

  // out = h_final @ Wy^T + by. h lines were never cached in L2 this launch,
  // so plain loads miss L2 and fetch fresh data from L3.
  if (g < 64) {
    const int o0 = g * 16;
    const unsigned short* Byb = Wyb + (size_t)(o0 + l16) * 1024 + kw + quad * 8;
    f32x4 acc[4] = {};
#pragma unroll
    for (int s = 0; s < 8; ++s) {
      const bf16x8 byf = *(const bf16x8*)(Byb + s * 32);
#pragma unroll
      for (int mt = 0; mt < 4; ++mt) {
        const bf16x8 afr = *(const bf16x8*)(hbc + (size_t)(mt * 16 + l16) * 1024 + kw + s * 32 + quad * 8);
        acc[mt] = __builtin_amdgcn_mfma_f32_16x16x32_bf16(afr, byf, acc[mt], 0, 0, 0);
      }
    }
#pragma unroll
    for (int mt = 0; mt < 4; ++mt)
#pragma unroll
      for (int r = 0; r < 4; ++r)
        red[wid][mt * 16 + quad * 4 + r][l16] = acc[mt][r];
    __syncthreads();
#pragma unroll
    for (int j = 0; j < 4; ++j) {
      const int p = j * 256 + tid;
      const int b = p >> 4, oc = p & 15;
      const float v = red[0][b][oc] + red[1][b][oc] + red[2][b][oc] + red[3][b][oc] + by[o0 + oc];
      out[(size_t)b * 1024 + o0 + oc] = v;
    }
  }
}

extern "C" void kernel_launch(void* const* d_in, const int* in_sizes, int n_in,
                              void* d_out, int out_size, void* d_ws, size_t ws_size,
                              hipStream_t stream) {
  const float* x = (const float*)d_in[0];
  const float* Wxh = (const float*)d_in[1];
  const float* bh = (const float*)d_in[2];
  const float* Whh = (const float*)d_in[3];
  const float* Wxz = (const float*)d_in[4];
  const float* bz = (const float*)d_in[5];
  const float* Whz = (const float*)d_in[6];
  const float* Wy = (const float*)d_in[7];
  const float* by = (const float*)d_in[8];
  float* out = (float*)d_out;

  char* ws = (char*)d_ws;
  size_t off = 0;
  auto alloc = [&](size_t bytes) -> void* {
    void* p = ws + off;
    off += (bytes + 255) & ~(size_t)255;
    return p;
  };
  const size_t nX = (size_t)BB * TT * DD;  // 33554432
  unsigned short* xb = (unsigned short*)alloc(nX * 2);                  // x bf16
  unsigned short* Wcat = (unsigned short*)alloc((size_t)2048 * 1024 * 2);  // [Wxh;Wxz] bf16
  unsigned short* WhzT = (unsigned short*)alloc((size_t)1024 * 1024 * 2);  // Whz^T bf16
  unsigned short* Wrec = (unsigned short*)alloc((size_t)2048 * 1024 * 2);  // [Whh;Mz] bf16
  unsigned short* Wyb = (unsigned short*)alloc((size_t)1024 * 1024 * 2);   // Wy bf16
  unsigned short* xhz = (unsigned short*)alloc((size_t)TT * BB * 2048 * 2);  // 128 MB
  unsigned short* hb0 = (unsigned short*)alloc((size_t)BB * RR * 2);
  unsigned short* hb1 = (unsigned short*)alloc((size_t)BB * RR * 2);
  unsigned int* flags = (unsigned int*)alloc(1024);

  hipMemsetAsync(hb0, 0, (size_t)BB * RR * 2, stream);
  hipMemsetAsync(flags, 0, 1024, stream);

  // weight / input conversions
  k_f2b4<<<dim3((unsigned)(nX / 4 / 256)), 256, 0, stream>>>(x, xb, (int)(nX / 4));
  k_f2b4<<<dim3(1024), 256, 0, stream>>>(Wxh, Wcat, 262144);
  k_f2b4<<<dim3(1024), 256, 0, stream>>>(Wxz, Wcat + 1024 * 1024, 262144);
  k_f2b4<<<dim3(1024), 256, 0, stream>>>(Whh, Wrec, 262144);
  k_f2b4<<<dim3(1024), 256, 0, stream>>>(Wy, Wyb, 262144);
  k_transpose_bf16<<<dim3(32, 32), dim3(32, 8), 0, stream>>>(Whz, WhzT);

  // Mz = Wxz @ Whz  -> Wrec rows 1024..2047
  gemm_bt<1><<<dim3(8, 8), 256, 0, stream>>>(Wcat + 1024 * 1024, WhzT, nullptr, nullptr,
                                             Wrec + (size_t)1024 * 1024, 1024);
  // xhz = x @ [Wxh;Wxz]^T + [bh;bz], time-major
  gemm_bt<0><<<dim3(16, 256), 256, 0, stream>>>(xb, Wcat, bh, bz, xhz, 1024);

  // cooperative launch (co-residency guarantee for the custom barrier)
  const unsigned short* xhz_c = xhz;
  const unsigned short* Wrec_c = Wrec;
  const unsigned short* Wyb_c = Wyb;
  const float* by_c = by;
  void* kargs[] = {(void*)&xhz_c, (void*)&Wrec_c, (void*)&Wyb_c, (void*)&by_c,
                   (void*)&hb0, (void*)&hb1, (void*)&flags, (void*)&out};
  hipLaunchCooperativeKernel((void*)scan_out_k, dim3(128), dim3(256), kargs, 0, stream);
}

// Round 4
// 3382.079 us; speedup vs baseline: 3.7496x; 1.8801x over previous
//
#include <hip/hip_runtime.h>

// Problem constants (fixed by the reference): B=64, T=512, D=1024, R=1024, O=1024
#define BB 64
#define TT 512
#define DD 1024
#define RR 1024

#define SCAN_BLOCKS 32
#define HS_STRIDE 1032            // staged h row stride in bf16 (1024 + 8 pad)
#define SCAN_LDS_BYTES (64 * HS_STRIDE * 2)   // 132096; red overlay needs 69632

typedef __bf16 bf16x8 __attribute__((ext_vector_type(8)));
typedef float f32x4 __attribute__((ext_vector_type(4)));
typedef unsigned short us4 __attribute__((ext_vector_type(4)));
typedef unsigned int u32x4 __attribute__((ext_vector_type(4)));
typedef unsigned long long u64;

__device__ inline unsigned short f2bf(float f) {
  unsigned int u = __float_as_uint(f);
  u = (u + 0x7fffu + ((u >> 16) & 1u)) >> 16;   // RNE
  return (unsigned short)u;
}
__device__ inline float bf2f(unsigned short b) {
  return __uint_as_float(((unsigned int)b) << 16);
}

// Coherent 16B load: bypasses L1/L2 (sc0 sc1), served by the coherence point.
// Caller must s_waitcnt vmcnt(0) (via asm) before using the result.
__device__ inline u32x4 ld16_sc(const void* p) {
  u32x4 r;
  asm volatile("global_load_dwordx4 %0, %1, off sc0 sc1"
               : "=v"(r) : "v"(p) : "memory");
  return r;
}

// ---- fp32 -> bf16 vectorized convert (n4 = n/4 groups) ----
__global__ void k_f2b4(const float* __restrict__ in, unsigned short* __restrict__ out, int n4) {
  int i = blockIdx.x * blockDim.x + threadIdx.x;
  if (i < n4) {
    const float4 v = ((const float4*)in)[i];
    us4 o;
    o.x = f2bf(v.x); o.y = f2bf(v.y); o.z = f2bf(v.z); o.w = f2bf(v.w);
    ((us4*)out)[i] = o;
  }
}

// ---- transpose 1024x1024 fp32 -> bf16 (out[j][k] = in[k][j]) ----
__global__ __launch_bounds__(256) void k_transpose_bf16(
    const float* __restrict__ in, unsigned short* __restrict__ out) {
  __shared__ float tile[32][33];
  const int bx = blockIdx.x * 32, by0 = blockIdx.y * 32;
  const int tx = threadIdx.x, ty = threadIdx.y;  // block (32,8)
#pragma unroll
  for (int r = 0; r < 32; r += 8)
    tile[ty + r][tx] = in[(size_t)(by0 + ty + r) * 1024 + bx + tx];
  __syncthreads();
#pragma unroll
  for (int r = 0; r < 32; r += 8)
    out[(size_t)(bx + ty + r) * 1024 + by0 + tx] = f2bf(tile[tx][ty + r]);
}

// ---- async global->LDS, 16B per lane ----
__device__ inline void gload_lds16(const unsigned short* g, unsigned short* l) {
  __builtin_amdgcn_global_load_lds(
      (const __attribute__((address_space(1))) unsigned int*)g,
      (__attribute__((address_space(3))) unsigned int*)l, 16, 0, 0);
}

// ---- bf16 GEMM, C[m,n] = sum_k A[m,k]*B[n,k], 128x128 tile, BK=32 ----
// EPI==0: out = xhz time-major [T][B][2048] bf16, bias folded (bh n<1024, bz else)
// EPI==1: out[m*1024+n] bf16 (Mz into Wrec rows 1024..2047)
template <int EPI>
__global__ __launch_bounds__(256) void gemm_bt(
    const unsigned short* __restrict__ A,
    const unsigned short* __restrict__ Bm,
    const float* __restrict__ bias_h,
    const float* __restrict__ bias_z,
    unsigned short* __restrict__ outb, int K) {
  __shared__ __attribute__((aligned(16))) unsigned short As[128 * 32];
  __shared__ __attribute__((aligned(16))) unsigned short Bs[128 * 32];
  const int tid = threadIdx.x;
  const int m0 = blockIdx.y * 128, n0 = blockIdx.x * 128;
  const int lane = tid & 63, wid = tid >> 6;
  const int l16 = lane & 15, quad = lane >> 4;
  const int wm = (wid & 1) * 64, wn = (wid >> 1) * 64;

  f32x4 acc[4][4] = {};

  const int c0 = tid, c1 = 256 + tid;
  const int rowA0 = c0 >> 2, colA0 = (c0 & 3) << 3;
  const int rowA1 = c1 >> 2, colA1 = (c1 & 3) << 3;

  for (int kk = 0; kk < K; kk += 32) {
    __syncthreads();
    gload_lds16(A + (size_t)(m0 + rowA0) * K + kk + colA0, As + c0 * 8);
    gload_lds16(A + (size_t)(m0 + rowA1) * K + kk + colA1, As + c1 * 8);
    gload_lds16(Bm + (size_t)(n0 + rowA0) * K + kk + colA0, Bs + c0 * 8);
    gload_lds16(Bm + (size_t)(n0 + rowA1) * K + kk + colA1, Bs + c1 * 8);
    __syncthreads();
    bf16x8 af[4], bfr[4];
#pragma unroll
    for (int i = 0; i < 4; ++i) {
      af[i] = *(const bf16x8*)&As[(wm + i * 16 + l16) * 32 + quad * 8];
      bfr[i] = *(const bf16x8*)&Bs[(wn + i * 16 + l16) * 32 + quad * 8];
    }
#pragma unroll
    for (int i = 0; i < 4; ++i)
#pragma unroll
      for (int j = 0; j < 4; ++j)
        acc[i][j] = __builtin_amdgcn_mfma_f32_16x16x32_bf16(af[i], bfr[j], acc[i][j], 0, 0, 0);
  }

#pragma unroll
  for (int i = 0; i < 4; ++i) {
#pragma unroll
    for (int j = 0; j < 4; ++j) {
#pragma unroll
      for (int r = 0; r < 4; ++r) {
        const int m = m0 + wm + i * 16 + quad * 4 + r;
        const int n = n0 + wn + j * 16 + l16;
        float v = acc[i][j][r];
        if (EPI == 0) {
          v += (n < 1024) ? bias_h[n] : bias_z[n - 1024];
          const int b = m >> 9;          // m = b*T + t, T=512
          const int t = m & 511;
          outb[((size_t)(t * 64 + b) << 11) + n] = f2bf(v);
        } else {
          outb[(size_t)m * 1024 + n] = f2bf(v);
        }
      }
    }
  }
}

// ---- persistent scan over T=512 steps + output GEMM ----
// 32 blocks x 1024 threads (16 waves = 4 K-slices x 4 n-subtiles). Block g
// owns h-cols [g*32, g*32+32); its 64 MFMA n-cols = 32 Whh rows + 32 Mz rows.
// Per step: stage full h (128 KB) global->LDS via 16B sc0/sc1 loads (coherent,
// L2-bypass, 8x fewer fabric packets than r3's 8B atomics), MFMA from LDS,
// K-reduce through LDS (overlaid on the stage region), elementwise update with
// fp32 register-resident master h, publish bf16 h' via relaxed AGENT atomics,
// fence-free flag barrier (r3-validated).
__global__ __launch_bounds__(1024) void scan_out_k(
    const unsigned short* __restrict__ xhz,   // [T][B][2048] bf16
    const unsigned short* __restrict__ Wrec,  // [2048][1024] bf16 (Whh ; Mz)
    const unsigned short* __restrict__ Wyb,   // [1024][1024] bf16
    const float* __restrict__ by,
    unsigned short* __restrict__ hb0, unsigned short* __restrict__ hb1,
    unsigned int* __restrict__ flags,
    float* __restrict__ out) {
  extern __shared__ char smem[];
  unsigned short* hs = (unsigned short*)smem;   // staged h [64][HS_STRIDE]
  float* red = (float*)smem;                    // overlay: [4][64][68] f32

  const int tid = threadIdx.x, g = blockIdx.x;
  const int lane = tid & 63, wid = tid >> 6;
  const int l16 = lane & 15, quad = lane >> 4;
  const int ks = wid >> 2, nsub = wid & 3;
  const int kw = ks * 256;                      // wave's K slice (bf16 elems)
  const int i0 = g * 32;

  // loop-invariant B fragments: 16 n-cols x 256 k slice -> 32 VGPRs (cached)
  const int bcol = (nsub < 2) ? (i0 + nsub * 16 + l16)
                              : (1024 + i0 + (nsub - 2) * 16 + l16);
  const unsigned short* Bb = Wrec + (size_t)bcol * 1024 + kw + quad * 8;
  bf16x8 bfr[8];
#pragma unroll
  for (int s = 0; s < 8; ++s) bfr[s] = *(const bf16x8*)(Bb + s * 32);

  // staging coords: thread copies 8 x 16B chunks of row sr (stride 256B)
  const int sr = tid >> 4;          // h row (b) 0..63
  const int su = tid & 15;          // 16B unit within row
  const unsigned short* gsrc_base0 = hb0 + sr * 1024 + su * 8;
  const unsigned short* gsrc_base1 = hb1 + sr * 1024 + su * 8;
  unsigned short* ldst = hs + sr * HS_STRIDE + su * 8;

  // elementwise coords: thread owns (b=eb, cols i0+ej, i0+ej+1)
  const int eb = tid >> 4, ej = (tid & 15) * 2;
  float hold0 = 0.0f, hold1 = 0.0f;   // fp32 master h, register-resident

  const unsigned short* hbc = hb0;
  unsigned short* hbn = hb1;
  const unsigned short* gsrc = gsrc_base0;

  for (int tt = 0; tt < TT; ++tt) {
    // ---- stage h -> LDS (16B coherent loads) + xhz prefetch ----
    u32x4 tmp[8];
#pragma unroll
    for (int c = 0; c < 8; ++c)
      tmp[c] = ld16_sc((const char*)gsrc + c * 256);
    const size_t xrow = ((size_t)(tt * 64 + eb)) << 11;
    const unsigned int xh2 = *(const unsigned int*)(xhz + xrow + i0 + ej);
    const unsigned int xz2 = *(const unsigned int*)(xhz + xrow + 1024 + i0 + ej);
    asm volatile("s_waitcnt vmcnt(0)" ::: "memory");
#pragma unroll
    for (int c = 0; c < 8; ++c)
      *(u32x4*)(ldst + c * 128) = tmp[c];       // c*256 bytes
    __syncthreads();

    // ---- MFMA: acc[mt] over 64 b-rows, this wave's (ks, nsub) ----
    f32x4 acc[4] = {};
#pragma unroll
    for (int s = 0; s < 8; ++s) {
#pragma unroll
      for (int mt = 0; mt < 4; ++mt) {
        const bf16x8 afr = *(const bf16x8*)(hs + (mt * 16 + l16) * HS_STRIDE + kw + s * 32 + quad * 8);
        acc[mt] = __builtin_amdgcn_mfma_f32_16x16x32_bf16(afr, bfr[s], acc[mt], 0, 0, 0);
      }
    }
    __syncthreads();   // all ds_reads of hs done; safe to overlay red

    // ---- K-reduction partials into LDS ----
#pragma unroll
    for (int mt = 0; mt < 4; ++mt)
#pragma unroll
      for (int r = 0; r < 4; ++r)
        red[(size_t)(ks * 64 + mt * 16 + quad * 4 + r) * 68 + nsub * 16 + l16] = acc[mt][r];
    __syncthreads();

    // ---- elementwise update (all 1024 threads, 2 elems each) ----
    float ph0 = 0.f, ph1 = 0.f, pz0 = 0.f, pz1 = 0.f;
#pragma unroll
    for (int w = 0; w < 4; ++w) {
      const float* rb = red + (size_t)(w * 64 + eb) * 68;
      ph0 += rb[ej]; ph1 += rb[ej + 1];
      pz0 += rb[32 + ej]; pz1 += rb[32 + ej + 1];
    }
    {
      const float xh0 = bf2f((unsigned short)(xh2 & 0xffff));
      const float xh1 = bf2f((unsigned short)(xh2 >> 16));
      const float xz0 = bf2f((unsigned short)(xz2 & 0xffff));
      const float xz1 = bf2f((unsigned short)(xz2 >> 16));
      const float z0 = 1.0f / (1.0f + __expf(-(xz0 + pz0)));
      const float z1 = 1.0f / (1.0f + __expf(-(xz1 + pz1)));
      const float hb_0 = fmaxf(xh0 + ph0, 0.0f);
      const float hb_1 = fmaxf(xh1 + ph1, 0.0f);
      hold0 = z0 * hold0 + (1.0f - z0) * hb_0;
      hold1 = z1 * hold1 + (1.0f - z1) * hb_1;
      const unsigned int pk = (unsigned int)f2bf(hold0) | ((unsigned int)f2bf(hold1) << 16);
      __hip_atomic_store((unsigned int*)(hbn + eb * 1024 + i0 + ej), pk,
                         __ATOMIC_RELAXED, __HIP_MEMORY_SCOPE_AGENT);
    }

    // ---- fence-free grid barrier (flags via coherence point) ----
    __syncthreads();   // drains each wave's vmcnt -> all h' stores visible
    if (tid == 0)
      __hip_atomic_store(&flags[g], (unsigned int)(tt + 1),
                         __ATOMIC_RELAXED, __HIP_MEMORY_SCOPE_AGENT);
    if (tid < 64) {
      const unsigned int tgt = (unsigned int)(tt + 1);
      unsigned int v;
      do {
        v = __hip_atomic_load(&flags[tid & 31], __ATOMIC_RELAXED, __HIP_MEMORY_SCOPE_AGENT);
      } while (__any(v < tgt));
    }
    __syncthreads();

    // swap buffers
    const unsigned short* tc = hbc; hbc = hbn; hbn = (unsigned short*)tc;
    gsrc = (tt & 1) ? gsrc_base0 : gsrc_base1;   // next source = buffer just written
  }

  // ---- epilogue: out = h_final @ Wy^T + by ----
  // stage final h (in hbc) into LDS
  {
    u32x4 tmp[8];
#pragma unroll
    for (int c = 0; c < 8; ++c)
      tmp[c] = ld16_sc((const char*)(hbc + sr * 1024 + su * 8) + c * 256);
    asm volatile("s_waitcnt vmcnt(0)" ::: "memory");
#pragma unroll
    for (int c = 0; c < 8; ++c)
      *(u32x4*)(ldst + c * 128) = tmp[c];
  }
  __syncthreads();

  if (nsub < 2) {   // 8 waves compute the block's 32 out-cols
    const int ocol = i0 + nsub * 16 + l16;
    const unsigned short* Byb = Wyb + (size_t)ocol * 1024 + kw + quad * 8;
    f32x4 acc[4] = {};
#pragma unroll
    for (int s = 0; s < 8; ++s) {
      const bf16x8 byf = *(const bf16x8*)(Byb + s * 32);
#pragma unroll
      for (int mt = 0; mt < 4; ++mt) {
        const bf16x8 afr = *(const bf16x8*)(hs + (mt * 16 + l16) * HS_STRIDE + kw + s * 32 + quad * 8);
        acc[mt] = __builtin_amdgcn_mfma_f32_16x16x32_bf16(afr, byf, acc[mt], 0, 0, 0);
      }
    }
    __syncthreads();   // hs reads done (only these waves read; others idle but sync below)
#pragma unroll
    for (int mt = 0; mt < 4; ++mt)
#pragma unroll
      for (int r = 0; r < 4; ++r)
        red[(size_t)(ks * 64 + mt * 16 + quad * 4 + r) * 68 + nsub * 16 + l16] = acc[mt][r];
  } else {
    __syncthreads();   // match the sync in the taken branch (wave-uniform nsub)
  }
  __syncthreads();

  {
    float o0 = by[i0 + ej], o1 = by[i0 + ej + 1];
#pragma unroll
    for (int w = 0; w < 4; ++w) {
      const float* rb = red + (size_t)(w * 64 + eb) * 68;
      o0 += rb[ej]; o1 += rb[ej + 1];
    }
    float2 ov; ov.x = o0; ov.y = o1;
    *(float2*)(out + (size_t)eb * 1024 + i0 + ej) = ov;
  }
}

extern "C" void kernel_launch(void* const* d_in, const int* in_sizes, int n_in,
                              void* d_out, int out_size, void* d_ws, size_t ws_size,
                              hipStream_t stream) {
  const float* x = (const float*)d_in[0];
  const float* Wxh = (const float*)d_in[1];
  const float* bh = (const float*)d_in[2];
  const float* Whh = (const float*)d_in[3];
  const float* Wxz = (const float*)d_in[4];
  const float* bz = (const float*)d_in[5];
  const float* Whz = (const float*)d_in[6];
  const float* Wy = (const float*)d_in[7];
  const float* by = (const float*)d_in[8];
  float* out = (float*)d_out;

  char* ws = (char*)d_ws;
  size_t off = 0;
  auto alloc = [&](size_t bytes) -> void* {
    void* p = ws + off;
    off += (bytes + 255) & ~(size_t)255;
    return p;
  };
  const size_t nX = (size_t)BB * TT * DD;  // 33554432
  unsigned short* xb = (unsigned short*)alloc(nX * 2);                  // x bf16
  unsigned short* Wcat = (unsigned short*)alloc((size_t)2048 * 1024 * 2);  // [Wxh;Wxz]
  unsigned short* WhzT = (unsigned short*)alloc((size_t)1024 * 1024 * 2);  // Whz^T
  unsigned short* Wrec = (unsigned short*)alloc((size_t)2048 * 1024 * 2);  // [Whh;Mz]
  unsigned short* Wyb = (unsigned short*)alloc((size_t)1024 * 1024 * 2);   // Wy bf16
  unsigned short* xhz = (unsigned short*)alloc((size_t)TT * BB * 2048 * 2);  // 128 MB
  unsigned short* hb0 = (unsigned short*)alloc((size_t)BB * RR * 2);
  unsigned short* hb1 = (unsigned short*)alloc((size_t)BB * RR * 2);
  unsigned int* flags = (unsigned int*)alloc(1024);

  hipMemsetAsync(hb0, 0, (size_t)BB * RR * 2, stream);
  hipMemsetAsync(flags, 0, 1024, stream);

  // weight / input conversions
  k_f2b4<<<dim3((unsigned)(nX / 4 / 256)), 256, 0, stream>>>(x, xb, (int)(nX / 4));
  k_f2b4<<<dim3(1024), 256, 0, stream>>>(Wxh, Wcat, 262144);
  k_f2b4<<<dim3(1024), 256, 0, stream>>>(Wxz, Wcat + 1024 * 1024, 262144);
  k_f2b4<<<dim3(1024), 256, 0, stream>>>(Whh, Wrec, 262144);
  k_f2b4<<<dim3(1024), 256, 0, stream>>>(Wy, Wyb, 262144);
  k_transpose_bf16<<<dim3(32, 32), dim3(32, 8), 0, stream>>>(Whz, WhzT);

  // Mz = Wxz @ Whz  -> Wrec rows 1024..2047
  gemm_bt<1><<<dim3(8, 8), 256, 0, stream>>>(Wcat + 1024 * 1024, WhzT, nullptr, nullptr,
                                             Wrec + (size_t)1024 * 1024, 1024);
  // xhz = x @ [Wxh;Wxz]^T + [bh;bz], time-major
  gemm_bt<0><<<dim3(16, 256), 256, 0, stream>>>(xb, Wcat, bh, bz, xhz, 1024);

  // cooperative launch; opt in to 129 KB dynamic LDS (idempotent, capture-safe)
  hipFuncSetAttribute((const void*)scan_out_k,
                      hipFuncAttributeMaxDynamicSharedMemorySize, SCAN_LDS_BYTES);
  const unsigned short* xhz_c = xhz;
  const unsigned short* Wrec_c = Wrec;
  const unsigned short* Wyb_c = Wyb;
  const float* by_c = by;
  void* kargs[] = {(void*)&xhz_c, (void*)&Wrec_c, (void*)&Wyb_c, (void*)&by_c,
                   (void*)&hb0, (void*)&hb1, (void*)&flags, (void*)&out};
  hipLaunchCooperativeKernel((void*)scan_out_k, dim3(SCAN_BLOCKS), dim3(1024),
                             kargs, SCAN_LDS_BYTES, stream);
}